// Round 6
// baseline (185.430 us; speedup 1.0000x reference)
//
#include <hip/hip_runtime.h>

typedef __bf16 bf16x8 __attribute__((ext_vector_type(8)));
typedef float f32x4 __attribute__((ext_vector_type(4)));
typedef unsigned int u32x4 __attribute__((ext_vector_type(4)));
typedef unsigned short u16;
typedef unsigned int u32;

#define AS1 __attribute__((address_space(1)))
#define AS3 __attribute__((address_space(3)))

__device__ __forceinline__ u16 f2bf(float f) {
  u32 u = __builtin_bit_cast(u32, f);
  u32 r = u + 0x7FFFu + ((u >> 16) & 1u);
  return (u16)(r >> 16);
}

// packed f32x2 -> bf16x2 (RTNE), single instruction on gfx950
__device__ __forceinline__ u32 cvtpk(float lo, float hi) {
  u32 r;
  asm("v_cvt_pk_bf16_f32 %0, %1, %2" : "=v"(r) : "v"(lo), "v"(hi));
  return r;
}

__device__ __forceinline__ void gload_lds16(const void* g, void* l) {
  __builtin_amdgcn_global_load_lds((AS1 void*)(void*)g, (AS3 void*)l, 16, 0, 0);
}

__device__ __forceinline__ f32x4 mfma16(bf16x8 a, bf16x8 b, f32x4 c) {
  return __builtin_amdgcn_mfma_f32_16x16x32_bf16(a, b, c, 0, 0, 0);
}

// ---------------- fp32 -> bf16 convert, all three tensors in one launch ----------------
__global__ void k_f2bf3(const float* __restrict__ a, const float* __restrict__ bb,
                        const float* __restrict__ c, u16* __restrict__ oa,
                        u16* __restrict__ ob, u16* __restrict__ oc) {
  int i = blockIdx.x * blockDim.x + threadIdx.x;
  int stride = gridDim.x * blockDim.x;
  for (; i < 2097152; i += stride) {
    const float* src; u16* dst; int j = i;
    if (j < 1048576)      { src = a;  dst = oa; }
    else if (j < 1835008) { src = bb; dst = ob; j -= 1048576; }
    else                  { src = c;  dst = oc; j -= 1835008; }
    float4 v = reinterpret_cast<const float4*>(src)[j];
    ushort4 o;
    o.x = f2bf(v.x); o.y = f2bf(v.y); o.z = f2bf(v.z); o.w = f2bf(v.w);
    reinterpret_cast<ushort4*>(dst)[j] = o;
  }
}

// ---------------- GEMM: C[m][n] = A[m][:] . B[n][:] + bias[n] ----------------
// EPI 0 (qkv proj): cols<1024 -> bf16 out scaled by 0.125*log2e (q);
//                   cols in [1024,2048) -> bf16 out (k);
//                   cols>=2048 -> written ONLY to vt (transposed+permuted V).
// EPI 1: fp32 out + bias.
template<int BM, int BN, int EPI>
__global__ __launch_bounds__(256, 2)
void k_gemm_bt(const u16* __restrict__ A, const u16* __restrict__ B,
               const float* __restrict__ bias, void* __restrict__ out,
               u16* __restrict__ vt, int M, int N, int K)
{
  __shared__ __align__(16) u16 sA[BM * 32];
  __shared__ __align__(16) u16 sB[BN * 32];
  const int tid = threadIdx.x;
  const int lane = tid & 63;
  const int wid = tid >> 6;
  const int wm = wid >> 1, wn = wid & 1;
  const int bm0 = blockIdx.y * BM;
  const int bn0 = blockIdx.x * BN;
  constexpr int FM = BM / 32;
  constexpr int FN = BN / 32;

  f32x4 acc[FM][FN];
#pragma unroll
  for (int i = 0; i < FM; ++i)
#pragma unroll
    for (int j = 0; j < FN; ++j)
      acc[i][j] = (f32x4){0.f, 0.f, 0.f, 0.f};

  constexpr int CA = BM / 16;
  constexpr int CB = BN / 16;
  const int nk = K >> 5;
  for (int kt = 0; kt < nk; ++kt) {
    __syncthreads();
    const char* gA = (const char*)(A + (size_t)bm0 * K + kt * 32);
#pragma unroll
    for (int c = 0; c < CA / 4; ++c) {
      int ch = c * 4 + wid;
      int o = ch * 1024 + lane * 16;
      gload_lds16(gA + (size_t)(o >> 6) * (K * 2) + (o & 63), (char*)sA + ch * 1024);
    }
    const char* gB = (const char*)(B + (size_t)bn0 * K + kt * 32);
#pragma unroll
    for (int c = 0; c < CB / 4; ++c) {
      int ch = c * 4 + wid;
      int o = ch * 1024 + lane * 16;
      gload_lds16(gB + (size_t)(o >> 6) * (K * 2) + (o & 63), (char*)sB + ch * 1024);
    }
    __syncthreads();
    bf16x8 af[FM], bfr[FN];
#pragma unroll
    for (int mi = 0; mi < FM; ++mi) {
      int row = wm * (BM / 2) + mi * 16 + (lane & 15);
      af[mi] = *(const bf16x8*)((const char*)sA + row * 64 + ((lane >> 4) << 4));
    }
#pragma unroll
    for (int ni = 0; ni < FN; ++ni) {
      int row = wn * (BN / 2) + ni * 16 + (lane & 15);
      bfr[ni] = *(const bf16x8*)((const char*)sB + row * 64 + ((lane >> 4) << 4));
    }
#pragma unroll
    for (int mi = 0; mi < FM; ++mi)
#pragma unroll
      for (int ni = 0; ni < FN; ++ni)
        acc[mi][ni] = mfma16(af[mi], bfr[ni], acc[mi][ni]);
  }

#pragma unroll
  for (int mi = 0; mi < FM; ++mi)
#pragma unroll
    for (int ni = 0; ni < FN; ++ni) {
      int row = bm0 + wm * (BM / 2) + mi * 16 + ((lane >> 4) << 2);
      int col = bn0 + wn * (BN / 2) + ni * 16 + (lane & 15);
      float bv = bias[col];
      if (EPI == 0) {
        if (col < 2048) {
          float sc = (col < 1024) ? 0.18033688011112042f : 1.0f;  // 0.125*log2(e)
          u16* O = (u16*)out;
#pragma unroll
          for (int r = 0; r < 4; ++r)
            O[(size_t)(row + r) * N + col] = f2bf((acc[mi][ni][r] + bv) * sc);
        } else {
          // V: write transposed + column-permuted into vt[bh][d][t'] only.
          int hh = (col - 2048) >> 6, dd = (col - 2048) & 63;
          int bb = row >> 11;        // batch (rows 0..2047 -> 0, 2048..4095 -> 1)
          int t  = row & 2047;       // multiple of 4
          int g  = ((t >> 5) & 1) * 8 + (((t >> 2) & 3) << 1) + ((t >> 4) & 1);
          u16* dst = vt + (size_t)((bb * 16 + hh) * 64 + dd) * 2048 + ((t >> 6) << 6) + g * 4;
          uint2 w;
          w.x = cvtpk(acc[mi][ni][0] + bv, acc[mi][ni][1] + bv);
          w.y = cvtpk(acc[mi][ni][2] + bv, acc[mi][ni][3] + bv);
          *(uint2*)dst = w;
        }
      } else {
        float* O = (float*)out;
#pragma unroll
        for (int r = 0; r < 4; ++r)
          O[(size_t)(row + r) * N + col] = acc[mi][ni][r] + bv;
      }
    }
}

// ---------------- fused causal flash attention, LDS-free ----------------
// Each wave = independent 16-row flash attention. K/V fragments read directly
// from global (L1/L2-resident; all 4 waves of a block read identical addresses
// -> L1 serves the reuse). No barriers, no LDS, no staging. Swapped QK^T,
// in-register softmax, P packed via cvt_pk into PV B-fragments (permuted vt).
// Grid 1024x256: bid pairs (u, u+512) get complementary qtiles (CU balance).
__global__ __launch_bounds__(256, 4)
void k_attn(const u16* __restrict__ qkv, const u16* __restrict__ vt, u16* __restrict__ yb)
{
  const int tid = threadIdx.x;
  const int lane = tid & 63;
  const int wid = tid >> 6;
  const int bid = blockIdx.x;
  const int half = bid >> 9;
  const int u = bid & 511;
  const int bh = u >> 4;                         // 0..31
  const int qs = u & 15;                         // 0..15
  const int qtile = half ? (31 - qs) : qs;       // 0..31 (64-row tiles)
  const int b = bh >> 4, h = bh & 15;
  const int wq0 = qtile * 64 + wid * 16;
  const int l15 = lane & 15;
  const int l4 = lane >> 4;

  // Q fragment (B-operand of swapped QK^T): lane holds Q[q=wq0+l15][32ks+l4*8..]
  bf16x8 qf[2];
#pragma unroll
  for (int ks = 0; ks < 2; ++ks)
    qf[ks] = *(const bf16x8*)(qkv + (size_t)(b * 2048 + wq0 + l15) * 3072 + h * 64 + ks * 32 + (l4 << 3));

  // per-lane base pointers for K and V fragment loads
  const u16* kptr = qkv + (size_t)(b * 2048 + l15) * 3072 + 1024 + h * 64 + (l4 << 3);
  const u16* vptr = vt + (size_t)bh * 131072 + (size_t)l15 * 2048 + (l4 << 3);

  f32x4 oacc[4];   // y^T: [q=l15][d=di*16+l4*4+r]
  float m = -1e30f, lsum = 0.f;
#pragma unroll
  for (int di = 0; di < 4; ++di) oacc[di] = (f32x4){0.f, 0.f, 0.f, 0.f};

  const int nt = qtile + 1;
  for (int t = 0; t < nt; ++t) {
    const int kv0 = t * 64;
    // ---- K fragments (identical addresses across the block's 4 waves -> L1 reuse)
    bf16x8 bk[2][4];
#pragma unroll
    for (int ks = 0; ks < 2; ++ks)
#pragma unroll
      for (int ki = 0; ki < 4; ++ki)
        bk[ks][ki] = *(const bf16x8*)(kptr + (size_t)(kv0 + ki * 16) * 3072 + ks * 32);
    // ---- QK^T (swapped): lane owns q=wq0+l15, kv=ki*16+l4*4+r
    f32x4 s[4];
#pragma unroll
    for (int ki = 0; ki < 4; ++ki) s[ki] = (f32x4){0.f, 0.f, 0.f, 0.f};
    __builtin_amdgcn_s_setprio(1);
#pragma unroll
    for (int ks = 0; ks < 2; ++ks)
#pragma unroll
      for (int ki = 0; ki < 4; ++ki)
        s[ki] = mfma16(bk[ks][ki], qf[ks], s[ki]);
    __builtin_amdgcn_s_setprio(0);
    // ---- V fragments issued now; latency hides under the softmax below
    bf16x8 bv[2][4];
#pragma unroll
    for (int ks = 0; ks < 2; ++ks)
#pragma unroll
      for (int di = 0; di < 4; ++di)
        bv[ks][di] = *(const bf16x8*)(vptr + (size_t)di * 32768 + kv0 + ks * 32);
    // ---- causal mask (last tile only)
    if (t == nt - 1) {
      int qa = wq0 + l15;
#pragma unroll
      for (int ki = 0; ki < 4; ++ki) {
        int kvb = kv0 + ki * 16 + l4 * 4;
#pragma unroll
        for (int rr = 0; rr < 4; ++rr)
          if (kvb + rr > qa) s[ki][rr] = -1e30f;
      }
    }
    // ---- online softmax, per-lane row; defer-max (THR=8, log2 domain)
    float rm = s[0][0];
#pragma unroll
    for (int ki = 0; ki < 4; ++ki)
#pragma unroll
      for (int rr = 0; rr < 4; ++rr)
        rm = fmaxf(rm, s[ki][rr]);
    rm = fmaxf(rm, __shfl_xor(rm, 16));
    rm = fmaxf(rm, __shfl_xor(rm, 32));
    float mo = m;
    float mn;
    if (__all(rm <= mo + 8.f)) {
      mn = mo;  // stable: skip rescale, P bounded by 2^8
    } else {
      mn = fmaxf(mo, rm);
      float f = exp2f(mo - mn);
      m = mn;
      lsum *= f;
#pragma unroll
      for (int di = 0; di < 4; ++di)
#pragma unroll
        for (int rr = 0; rr < 4; ++rr)
          oacc[di][rr] *= f;
    }
    u32 pk_[4][2];
    float rs = 0.f;
#pragma unroll
    for (int ki = 0; ki < 4; ++ki) {
      float p0 = exp2f(s[ki][0] - mn);
      float p1 = exp2f(s[ki][1] - mn);
      float p2 = exp2f(s[ki][2] - mn);
      float p3 = exp2f(s[ki][3] - mn);
      rs += (p0 + p1) + (p2 + p3);
      pk_[ki][0] = cvtpk(p0, p1);
      pk_[ki][1] = cvtpk(p2, p3);
    }
    rs += __shfl_xor(rs, 16);
    rs += __shfl_xor(rs, 32);
    lsum += rs;
    // ---- PV: vt column permutation makes the k-index mapping match both operands
    __builtin_amdgcn_s_setprio(1);
#pragma unroll
    for (int ks = 0; ks < 2; ++ks) {
      u32x4 w0 = {pk_[2 * ks][0], pk_[2 * ks][1], pk_[2 * ks + 1][0], pk_[2 * ks + 1][1]};
      bf16x8 pb = __builtin_bit_cast(bf16x8, w0);
#pragma unroll
      for (int di = 0; di < 4; ++di)
        oacc[di] = mfma16(bv[ks][di], pb, oacc[di]);
    }
    __builtin_amdgcn_s_setprio(0);
  }
  // ---- epilogue: normalize, pack 4 consecutive d per 8B store
  float inv = 1.f / lsum;
  size_t rowb = (size_t)(b * 2048 + wq0 + l15) * 1024 + h * 64 + l4 * 4;
#pragma unroll
  for (int di = 0; di < 4; ++di) {
    uint2 w;
    w.x = cvtpk(oacc[di][0] * inv, oacc[di][1] * inv);
    w.y = cvtpk(oacc[di][2] * inv, oacc[di][3] * inv);
    *(uint2*)(yb + rowb + di * 16) = w;
  }
}

extern "C" void kernel_launch(void* const* d_in, const int* in_sizes, int n_in,
                              void* d_out, int out_size, void* d_ws, size_t ws_size,
                              hipStream_t stream)
{
  (void)in_sizes; (void)n_in; (void)out_size; (void)ws_size;
  const float* x      = (const float*)d_in[0];
  const float* w_attn = (const float*)d_in[1];
  const float* b_attn = (const float*)d_in[2];
  const float* w_proj = (const float*)d_in[3];
  const float* b_proj = (const float*)d_in[4];
  float* out = (float*)d_out;
  char* ws = (char*)d_ws;
  u16* xb  = (u16*)(ws);                 // 4096x1024 bf16
  u16* wab = (u16*)(ws + 8388608);       // 3072x1024 bf16
  u16* wpb = (u16*)(ws + 14680064);      // 1024x1024 bf16
  u16* qkv = (u16*)(ws + 16777216);      // 4096x3072 bf16 (v region unused)
  u16* vt  = (u16*)(ws + 41943040);      // 32x64x2048 bf16 (permuted cols)
  u16* yb  = (u16*)(ws + 50331648);      // 4096x1024 bf16

  k_f2bf3<<<2048, 256, 0, stream>>>(x, w_attn, w_proj, xb, wab, wpb);
  k_gemm_bt<128, 128, 0><<<dim3(24, 32), 256, 0, stream>>>(xb, wab, b_attn, qkv, vt, 4096, 3072, 1024);
  k_attn<<<1024, 256, 0, stream>>>(qkv, vt, yb);
  k_gemm_bt<64, 128, 1><<<dim3(8, 64), 256, 0, stream>>>(yb, wpb, b_proj, out, nullptr, 4096, 1024, 1024);
}

// Round 7
// 122.751 us; speedup vs baseline: 1.5106x; 1.5106x over previous
//
#include <hip/hip_runtime.h>

typedef __bf16 bf16x8 __attribute__((ext_vector_type(8)));
typedef float f32x4 __attribute__((ext_vector_type(4)));
typedef unsigned int u32x4 __attribute__((ext_vector_type(4)));
typedef unsigned short u16;
typedef unsigned int u32;

#define AS1 __attribute__((address_space(1)))
#define AS3 __attribute__((address_space(3)))

__device__ __forceinline__ u16 f2bf(float f) {
  u32 u = __builtin_bit_cast(u32, f);
  u32 r = u + 0x7FFFu + ((u >> 16) & 1u);
  return (u16)(r >> 16);
}

// packed f32x2 -> bf16x2 (RTNE), single instruction on gfx950
__device__ __forceinline__ u32 cvtpk(float lo, float hi) {
  u32 r;
  asm("v_cvt_pk_bf16_f32 %0, %1, %2" : "=v"(r) : "v"(lo), "v"(hi));
  return r;
}

__device__ __forceinline__ void gload_lds16(const void* g, void* l) {
  __builtin_amdgcn_global_load_lds((AS1 void*)(void*)g, (AS3 void*)l, 16, 0, 0);
}

__device__ __forceinline__ f32x4 mfma16(bf16x8 a, bf16x8 b, f32x4 c) {
  return __builtin_amdgcn_mfma_f32_16x16x32_bf16(a, b, c, 0, 0, 0);
}

// ---------------- fp32 -> bf16 convert, all three tensors in one launch ----------------
__global__ void k_f2bf3(const float* __restrict__ a, const float* __restrict__ bb,
                        const float* __restrict__ c, u16* __restrict__ oa,
                        u16* __restrict__ ob, u16* __restrict__ oc) {
  int i = blockIdx.x * blockDim.x + threadIdx.x;
  int stride = gridDim.x * blockDim.x;
  for (; i < 2097152; i += stride) {
    const float* src; u16* dst; int j = i;
    if (j < 1048576)      { src = a;  dst = oa; }
    else if (j < 1835008) { src = bb; dst = ob; j -= 1048576; }
    else                  { src = c;  dst = oc; j -= 1835008; }
    float4 v = reinterpret_cast<const float4*>(src)[j];
    ushort4 o;
    o.x = f2bf(v.x); o.y = f2bf(v.y); o.z = f2bf(v.z); o.w = f2bf(v.w);
    reinterpret_cast<ushort4*>(dst)[j] = o;
  }
}

// ---------------- GEMM: C[m][n] = A[m][:] . B[n][:] + bias[n] ----------------
// 2-phase prefetch: double-buffered LDS, stage(kt+1) issued before compute(kt),
// ONE barrier per K-step (its vmcnt(0) drain publishes the staged buffer).
// EPI 0 (qkv proj): cols<1024 -> bf16 scaled by 0.125*log2e (q);
//                   [1024,2048) -> bf16 (k); >=2048 -> vt (transposed+permuted V).
// EPI 1: fp32 out + bias.
template<int BM, int BN, int EPI>
__global__ __launch_bounds__(256, 2)
void k_gemm_bt(const u16* __restrict__ A, const u16* __restrict__ B,
               const float* __restrict__ bias, void* __restrict__ out,
               u16* __restrict__ vt, int M, int N, int K)
{
  __shared__ __align__(16) u16 sA[2][BM * 32];
  __shared__ __align__(16) u16 sB[2][BN * 32];
  const int tid = threadIdx.x;
  const int lane = tid & 63;
  const int wid = tid >> 6;
  const int wm = wid >> 1, wn = wid & 1;
  const int bm0 = blockIdx.y * BM;
  const int bn0 = blockIdx.x * BN;
  constexpr int FM = BM / 32;
  constexpr int FN = BN / 32;

  f32x4 acc[FM][FN];
#pragma unroll
  for (int i = 0; i < FM; ++i)
#pragma unroll
    for (int j = 0; j < FN; ++j)
      acc[i][j] = (f32x4){0.f, 0.f, 0.f, 0.f};

  constexpr int CA = BM / 16;  // 1KB chunks in A tile
  constexpr int CB = BN / 16;

  auto stage = [&](int kt, int buf) {
    const char* gA = (const char*)(A + (size_t)bm0 * K + kt * 32);
#pragma unroll
    for (int c = 0; c < CA / 4; ++c) {
      int ch = c * 4 + wid;
      int o = ch * 1024 + lane * 16;
      gload_lds16(gA + (size_t)(o >> 6) * (K * 2) + (o & 63), (char*)sA[buf] + ch * 1024);
    }
    const char* gB = (const char*)(B + (size_t)bn0 * K + kt * 32);
#pragma unroll
    for (int c = 0; c < CB / 4; ++c) {
      int ch = c * 4 + wid;
      int o = ch * 1024 + lane * 16;
      gload_lds16(gB + (size_t)(o >> 6) * (K * 2) + (o & 63), (char*)sB[buf] + ch * 1024);
    }
  };

  const int nk = K >> 5;
  int cur = 0;
  stage(0, 0);
  __syncthreads();
  for (int kt = 0; kt < nk; ++kt) {
    if (kt + 1 < nk) stage(kt + 1, cur ^ 1);  // prefetch; drains at the barrier below
    bf16x8 af[FM], bfr[FN];
#pragma unroll
    for (int mi = 0; mi < FM; ++mi) {
      int row = wm * (BM / 2) + mi * 16 + (lane & 15);
      af[mi] = *(const bf16x8*)((const char*)sA[cur] + row * 64 + ((lane >> 4) << 4));
    }
#pragma unroll
    for (int ni = 0; ni < FN; ++ni) {
      int row = wn * (BN / 2) + ni * 16 + (lane & 15);
      bfr[ni] = *(const bf16x8*)((const char*)sB[cur] + row * 64 + ((lane >> 4) << 4));
    }
#pragma unroll
    for (int mi = 0; mi < FM; ++mi)
#pragma unroll
      for (int ni = 0; ni < FN; ++ni)
        acc[mi][ni] = mfma16(af[mi], bfr[ni], acc[mi][ni]);
    __syncthreads();  // publishes buf[cur^1]
    cur ^= 1;
  }

#pragma unroll
  for (int mi = 0; mi < FM; ++mi)
#pragma unroll
    for (int ni = 0; ni < FN; ++ni) {
      int row = bm0 + wm * (BM / 2) + mi * 16 + ((lane >> 4) << 2);
      int col = bn0 + wn * (BN / 2) + ni * 16 + (lane & 15);
      float bv = bias[col];
      if (EPI == 0) {
        if (col < 2048) {
          float sc = (col < 1024) ? 0.18033688011112042f : 1.0f;  // 0.125*log2(e)
          u16* O = (u16*)out;
#pragma unroll
          for (int r = 0; r < 4; ++r)
            O[(size_t)(row + r) * N + col] = f2bf((acc[mi][ni][r] + bv) * sc);
        } else {
          // V: write transposed + column-permuted into vt[bh][d][t'] only.
          int hh = (col - 2048) >> 6, dd = (col - 2048) & 63;
          int bb = row >> 11;
          int t  = row & 2047;       // multiple of 4
          int g  = ((t >> 5) & 1) * 8 + (((t >> 2) & 3) << 1) + ((t >> 4) & 1);
          u16* dst = vt + (size_t)((bb * 16 + hh) * 64 + dd) * 2048 + ((t >> 6) << 6) + g * 4;
          uint2 w;
          w.x = cvtpk(acc[mi][ni][0] + bv, acc[mi][ni][1] + bv);
          w.y = cvtpk(acc[mi][ni][2] + bv, acc[mi][ni][3] + bv);
          *(uint2*)dst = w;
        }
      } else {
        float* O = (float*)out;
#pragma unroll
        for (int r = 0; r < 4; ++r)
          O[(size_t)(row + r) * N + col] = acc[mi][ni][r] + bv;
      }
    }
}

// ---------------- fused causal flash attention (round-4 known-good) ----------------
// 64 q-rows per block (4 waves x 16 rows), swapped QK^T, in-register softmax,
// P packed via cvt_pk straight into PV B-fragments (permuted V). Grid 1024:
// bid pairs (u, u+512) get complementary qtiles for CU load balance.
__global__ __launch_bounds__(256, 4)
void k_attn(const u16* __restrict__ qkv, const u16* __restrict__ vt, u16* __restrict__ yb)
{
  __shared__ __align__(16) u16 sK[2][64 * 64];   // [kv][d], chunk-swizzled
  __shared__ __align__(16) u16 sV[2][64 * 64];   // [d][kv'] permuted V, chunk-swizzled
  const int tid = threadIdx.x;
  const int lane = tid & 63;
  const int wid = tid >> 6;
  const int bid = blockIdx.x;
  const int half = bid >> 9;
  const int u = bid & 511;
  const int bh = u >> 4;                         // 0..31
  const int qs = u & 15;                         // 0..15
  const int qtile = half ? (31 - qs) : qs;       // 0..31 (64-row tiles)
  const int b = bh >> 4, h = bh & 15;
  const int q0 = qtile * 64;
  const int wq0 = q0 + wid * 16;
  const int l15 = lane & 15;
  const int l4 = lane >> 4;

  bf16x8 qf[2];
#pragma unroll
  for (int ks = 0; ks < 2; ++ks) {
    const u16* src = qkv + (size_t)(b * 2048 + wq0 + l15) * 3072 + h * 64 + ks * 32 + (l4 << 3);
    qf[ks] = *(const bf16x8*)src;
  }

  f32x4 oacc[4];   // y^T: [q=l15][d=di*16+l4*4+r]
  float m = -1e30f, lsum = 0.f;
#pragma unroll
  for (int di = 0; di < 4; ++di) oacc[di] = (f32x4){0.f, 0.f, 0.f, 0.f};

  auto stage = [&](int kv0, int buf) {
    const char* gK = (const char*)(qkv + (size_t)(b * 2048 + kv0) * 3072 + 1024 + h * 64);
    const char* gV = (const char*)(vt + (size_t)bh * 131072 + kv0);
#pragma unroll
    for (int i = 0; i < 2; ++i) {
      int ch = wid * 2 + i;
      int o = ch * 1024 + lane * 16;
      int row = o >> 7;
      int cs = ((o >> 4) & 7) ^ (row & 7);  // pre-swizzled global source chunk
      gload_lds16(gK + (size_t)row * 6144 + cs * 16, (char*)sK[buf] + ch * 1024);
      gload_lds16(gV + (size_t)row * 4096 + cs * 16, (char*)sV[buf] + ch * 1024);
    }
  };

  const int nt = qtile + 1;
  int cur = 0;
  stage(0, 0);
  __syncthreads();
  for (int t = 0; t < nt; ++t) {
    const int kv0 = t * 64;
    if (t + 1 < nt) stage((t + 1) * 64, cur ^ 1);  // prefetch next tile
    const bool active = (kv0 <= wq0 + 15);
    if (active) {
      f32x4 s[4];
#pragma unroll
      for (int ki = 0; ki < 4; ++ki) s[ki] = (f32x4){0.f, 0.f, 0.f, 0.f};
#pragma unroll
      for (int ks = 0; ks < 2; ++ks) {
        bf16x8 bk[4];
#pragma unroll
        for (int ki = 0; ki < 4; ++ki) {
          int row = ki * 16 + l15;
          int cc = (ks * 4 + l4) ^ (row & 7);
          bk[ki] = *(const bf16x8*)((const char*)sK[cur] + row * 128 + cc * 16);
        }
#pragma unroll
        for (int ki = 0; ki < 4; ++ki)
          s[ki] = mfma16(bk[ki], qf[ks], s[ki]);
      }
      if (kv0 + 63 > wq0) {  // causal mask (boundary tiles only)
        int qa = wq0 + l15;
#pragma unroll
        for (int ki = 0; ki < 4; ++ki) {
          int kvb = kv0 + ki * 16 + l4 * 4;
#pragma unroll
          for (int rr = 0; rr < 4; ++rr)
            if (kvb + rr > qa) s[ki][rr] = -1e30f;
        }
      }
      // online softmax, per-lane row; defer-max (THR=8, log2 domain)
      float rm = s[0][0];
#pragma unroll
      for (int ki = 0; ki < 4; ++ki)
#pragma unroll
        for (int rr = 0; rr < 4; ++rr)
          rm = fmaxf(rm, s[ki][rr]);
      rm = fmaxf(rm, __shfl_xor(rm, 16));
      rm = fmaxf(rm, __shfl_xor(rm, 32));
      float mo = m;
      float mn;
      if (__all(rm <= mo + 8.f)) {
        mn = mo;  // stable: skip rescale, P bounded by 2^8
      } else {
        mn = fmaxf(mo, rm);
        float f = exp2f(mo - mn);
        m = mn;
        lsum *= f;
#pragma unroll
        for (int di = 0; di < 4; ++di)
#pragma unroll
          for (int rr = 0; rr < 4; ++rr)
            oacc[di][rr] *= f;
      }
      u32 pk_[4][2];
      float rs = 0.f;
#pragma unroll
      for (int ki = 0; ki < 4; ++ki) {
        float p0 = exp2f(s[ki][0] - mn);
        float p1 = exp2f(s[ki][1] - mn);
        float p2 = exp2f(s[ki][2] - mn);
        float p3 = exp2f(s[ki][3] - mn);
        rs += (p0 + p1) + (p2 + p3);
        pk_[ki][0] = cvtpk(p0, p1);
        pk_[ki][1] = cvtpk(p2, p3);
      }
      rs += __shfl_xor(rs, 16);
      rs += __shfl_xor(rs, 32);
      lsum += rs;
      // PV: V column permutation makes k-index mapping match on both operands
#pragma unroll
      for (int ks = 0; ks < 2; ++ks) {
        u32x4 w0 = {pk_[2 * ks][0], pk_[2 * ks][1], pk_[2 * ks + 1][0], pk_[2 * ks + 1][1]};
        bf16x8 pb = __builtin_bit_cast(bf16x8, w0);
#pragma unroll
        for (int di = 0; di < 4; ++di) {
          int row = di * 16 + l15;
          int cc = (ks * 4 + l4) ^ (row & 7);
          bf16x8 bv = *(const bf16x8*)((const char*)sV[cur] + row * 128 + cc * 16);
          oacc[di] = mfma16(bv, pb, oacc[di]);
        }
      }
    }
    __syncthreads();  // drains vmcnt(0): publishes buf[cur^1]
    cur ^= 1;
  }
  float inv = 1.f / lsum;
  size_t rowb = (size_t)(b * 2048 + wq0 + l15) * 1024 + h * 64 + l4 * 4;
#pragma unroll
  for (int di = 0; di < 4; ++di) {
    uint2 w;
    w.x = cvtpk(oacc[di][0] * inv, oacc[di][1] * inv);
    w.y = cvtpk(oacc[di][2] * inv, oacc[di][3] * inv);
    *(uint2*)(yb + rowb + di * 16) = w;
  }
}

extern "C" void kernel_launch(void* const* d_in, const int* in_sizes, int n_in,
                              void* d_out, int out_size, void* d_ws, size_t ws_size,
                              hipStream_t stream)
{
  (void)in_sizes; (void)n_in; (void)out_size; (void)ws_size;
  const float* x      = (const float*)d_in[0];
  const float* w_attn = (const float*)d_in[1];
  const float* b_attn = (const float*)d_in[2];
  const float* w_proj = (const float*)d_in[3];
  const float* b_proj = (const float*)d_in[4];
  float* out = (float*)d_out;
  char* ws = (char*)d_ws;
  u16* xb  = (u16*)(ws);                 // 4096x1024 bf16
  u16* wab = (u16*)(ws + 8388608);       // 3072x1024 bf16
  u16* wpb = (u16*)(ws + 14680064);      // 1024x1024 bf16
  u16* qkv = (u16*)(ws + 16777216);      // 4096x3072 bf16 (v region unused)
  u16* vt  = (u16*)(ws + 41943040);      // 32x64x2048 bf16 (permuted cols)
  u16* yb  = (u16*)(ws + 50331648);      // 4096x1024 bf16

  k_f2bf3<<<2048, 256, 0, stream>>>(x, w_attn, w_proj, xb, wab, wpb);
  k_gemm_bt<256, 128, 0><<<dim3(24, 16), 256, 0, stream>>>(xb, wab, b_attn, qkv, vt, 4096, 3072, 1024);
  k_attn<<<1024, 256, 0, stream>>>(qkv, vt, yb);
  k_gemm_bt<64, 128, 1><<<dim3(8, 64), 256, 0, stream>>>(yb, wpb, b_proj, out, nullptr, 4096, 1024, 1024);
}

// Round 8
// 115.656 us; speedup vs baseline: 1.6033x; 1.0613x over previous
//
#include <hip/hip_runtime.h>

typedef __bf16 bf16x8 __attribute__((ext_vector_type(8)));
typedef float f32x4 __attribute__((ext_vector_type(4)));
typedef unsigned int u32x4 __attribute__((ext_vector_type(4)));
typedef unsigned short u16;
typedef unsigned int u32;

#define AS1 __attribute__((address_space(1)))
#define AS3 __attribute__((address_space(3)))

__device__ __forceinline__ u16 f2bf(float f) {
  u32 u = __builtin_bit_cast(u32, f);
  u32 r = u + 0x7FFFu + ((u >> 16) & 1u);
  return (u16)(r >> 16);
}

// packed f32x2 -> bf16x2 (RTNE), single instruction on gfx950
__device__ __forceinline__ u32 cvtpk(float lo, float hi) {
  u32 r;
  asm("v_cvt_pk_bf16_f32 %0, %1, %2" : "=v"(r) : "v"(lo), "v"(hi));
  return r;
}

__device__ __forceinline__ void gload_lds16(const void* g, void* l) {
  __builtin_amdgcn_global_load_lds((AS1 void*)(void*)g, (AS3 void*)l, 16, 0, 0);
}

__device__ __forceinline__ f32x4 mfma16(bf16x8 a, bf16x8 b, f32x4 c) {
  return __builtin_amdgcn_mfma_f32_16x16x32_bf16(a, b, c, 0, 0, 0);
}

// ---------------- fp32 -> bf16 convert, all three tensors in one launch ----------------
__global__ void k_f2bf3(const float* __restrict__ a, const float* __restrict__ bb,
                        const float* __restrict__ c, u16* __restrict__ oa,
                        u16* __restrict__ ob, u16* __restrict__ oc) {
  int i = blockIdx.x * blockDim.x + threadIdx.x;
  int stride = gridDim.x * blockDim.x;
  for (; i < 2097152; i += stride) {
    const float* src; u16* dst; int j = i;
    if (j < 1048576)      { src = a;  dst = oa; }
    else if (j < 1835008) { src = bb; dst = ob; j -= 1048576; }
    else                  { src = c;  dst = oc; j -= 1835008; }
    float4 v = reinterpret_cast<const float4*>(src)[j];
    ushort4 o;
    o.x = f2bf(v.x); o.y = f2bf(v.y); o.z = f2bf(v.z); o.w = f2bf(v.w);
    reinterpret_cast<ushort4*>(dst)[j] = o;
  }
}

// ---------------- GEMM: C[m][n] = A[m][:] . B[n][:] + bias[n] ----------------
// 2-phase prefetch: double-buffered LDS, stage(kt+1) issued before compute(kt),
// ONE barrier per K-step (its vmcnt(0) drain publishes the staged buffer).
template<int BM, int BN, int EPI>
__global__ __launch_bounds__(256, 2)
void k_gemm_bt(const u16* __restrict__ A, const u16* __restrict__ B,
               const float* __restrict__ bias, void* __restrict__ out,
               u16* __restrict__ vt, int M, int N, int K)
{
  __shared__ __align__(16) u16 sA[2][BM * 32];
  __shared__ __align__(16) u16 sB[2][BN * 32];
  const int tid = threadIdx.x;
  const int lane = tid & 63;
  const int wid = tid >> 6;
  const int wm = wid >> 1, wn = wid & 1;
  const int bm0 = blockIdx.y * BM;
  const int bn0 = blockIdx.x * BN;
  constexpr int FM = BM / 32;
  constexpr int FN = BN / 32;

  f32x4 acc[FM][FN];
#pragma unroll
  for (int i = 0; i < FM; ++i)
#pragma unroll
    for (int j = 0; j < FN; ++j)
      acc[i][j] = (f32x4){0.f, 0.f, 0.f, 0.f};

  constexpr int CA = BM / 16;  // 1KB chunks in A tile
  constexpr int CB = BN / 16;

  auto stage = [&](int kt, int buf) {
    const char* gA = (const char*)(A + (size_t)bm0 * K + kt * 32);
#pragma unroll
    for (int c = 0; c < CA / 4; ++c) {
      int ch = c * 4 + wid;
      int o = ch * 1024 + lane * 16;
      gload_lds16(gA + (size_t)(o >> 6) * (K * 2) + (o & 63), (char*)sA[buf] + ch * 1024);
    }
    const char* gB = (const char*)(B + (size_t)bn0 * K + kt * 32);
#pragma unroll
    for (int c = 0; c < CB / 4; ++c) {
      int ch = c * 4 + wid;
      int o = ch * 1024 + lane * 16;
      gload_lds16(gB + (size_t)(o >> 6) * (K * 2) + (o & 63), (char*)sB[buf] + ch * 1024);
    }
  };

  const int nk = K >> 5;
  int cur = 0;
  stage(0, 0);
  __syncthreads();
  for (int kt = 0; kt < nk; ++kt) {
    if (kt + 1 < nk) stage(kt + 1, cur ^ 1);  // prefetch; drains at the barrier below
    bf16x8 af[FM], bfr[FN];
#pragma unroll
    for (int mi = 0; mi < FM; ++mi) {
      int row = wm * (BM / 2) + mi * 16 + (lane & 15);
      af[mi] = *(const bf16x8*)((const char*)sA[cur] + row * 64 + ((lane >> 4) << 4));
    }
#pragma unroll
    for (int ni = 0; ni < FN; ++ni) {
      int row = wn * (BN / 2) + ni * 16 + (lane & 15);
      bfr[ni] = *(const bf16x8*)((const char*)sB[cur] + row * 64 + ((lane >> 4) << 4));
    }
#pragma unroll
    for (int mi = 0; mi < FM; ++mi)
#pragma unroll
      for (int ni = 0; ni < FN; ++ni)
        acc[mi][ni] = mfma16(af[mi], bfr[ni], acc[mi][ni]);
    __syncthreads();  // publishes buf[cur^1]
    cur ^= 1;
  }

#pragma unroll
  for (int mi = 0; mi < FM; ++mi)
#pragma unroll
    for (int ni = 0; ni < FN; ++ni) {
      int row = bm0 + wm * (BM / 2) + mi * 16 + ((lane >> 4) << 2);
      int col = bn0 + wn * (BN / 2) + ni * 16 + (lane & 15);
      float bv = bias[col];
      if (EPI == 0) {
        if (col < 2048) {
          float sc = (col < 1024) ? 0.18033688011112042f : 1.0f;  // 0.125*log2(e)
          u16* O = (u16*)out;
#pragma unroll
          for (int r = 0; r < 4; ++r)
            O[(size_t)(row + r) * N + col] = f2bf((acc[mi][ni][r] + bv) * sc);
        } else {
          // V: write transposed + column-permuted into vt[bh][d][t'] only.
          int hh = (col - 2048) >> 6, dd = (col - 2048) & 63;
          int bb = row >> 11;
          int t  = row & 2047;       // multiple of 4
          int g  = ((t >> 5) & 1) * 8 + (((t >> 2) & 3) << 1) + ((t >> 4) & 1);
          u16* dst = vt + (size_t)((bb * 16 + hh) * 64 + dd) * 2048 + ((t >> 6) << 6) + g * 4;
          uint2 w;
          w.x = cvtpk(acc[mi][ni][0] + bv, acc[mi][ni][1] + bv);
          w.y = cvtpk(acc[mi][ni][2] + bv, acc[mi][ni][3] + bv);
          *(uint2*)dst = w;
        }
      } else {
        float* O = (float*)out;
#pragma unroll
        for (int r = 0; r < 4; ++r)
          O[(size_t)(row + r) * N + col] = acc[mi][ni][r] + bv;
      }
    }
}

// ---------------- fused causal flash attention, pass 1 (kv-split tasks) ----------------
// Tasks of <=16 kv-tiles for uniform duration + dispatch refill (grid 1536 >
// resident capacity 1280). q<=15: single chunk, writes final yb. q>=16: two
// chunks write fp32 partials {O, m, l}; k_comb merges them.
// Task order is longest-first: tidx<32 -> (q=31-tidx, c=0); tidx>=32 -> (q=63-tidx, c=1).
__global__ __launch_bounds__(256, 5)
void k_attn(const u16* __restrict__ qkv, const u16* __restrict__ vt, u16* __restrict__ yb,
            float* __restrict__ PO, float* __restrict__ PML)
{
  __shared__ __align__(16) u16 sK[2][64 * 64];   // [kv][d], chunk-swizzled
  __shared__ __align__(16) u16 sV[2][64 * 64];   // [d][kv'] permuted V, chunk-swizzled
  const int tid = threadIdx.x;
  const int lane = tid & 63;
  const int wid = tid >> 6;
  const int bid = blockIdx.x;
  const int tidx = bid >> 5;                     // 0..47
  const int bh = bid & 31;
  const int cch = (tidx >= 32) ? 1 : 0;
  const int q = (tidx < 32) ? (31 - tidx) : (63 - tidx);
  const int single = (q <= 15);
  const int b = bh >> 4, h = bh & 15;
  const int wq0 = q * 64 + wid * 16;
  const int l15 = lane & 15;
  const int l4 = lane >> 4;

  bf16x8 qf[2];
#pragma unroll
  for (int ks = 0; ks < 2; ++ks) {
    const u16* src = qkv + (size_t)(b * 2048 + wq0 + l15) * 3072 + h * 64 + ks * 32 + (l4 << 3);
    qf[ks] = *(const bf16x8*)src;
  }

  f32x4 oacc[4];   // y^T: [q=l15][d=di*16+l4*4+r]
  float m = -1e30f, lsum = 0.f;
#pragma unroll
  for (int di = 0; di < 4; ++di) oacc[di] = (f32x4){0.f, 0.f, 0.f, 0.f};

  auto stage = [&](int kv0, int buf) {
    const char* gK = (const char*)(qkv + (size_t)(b * 2048 + kv0) * 3072 + 1024 + h * 64);
    const char* gV = (const char*)(vt + (size_t)bh * 131072 + kv0);
#pragma unroll
    for (int i = 0; i < 2; ++i) {
      int ch = wid * 2 + i;
      int o = ch * 1024 + lane * 16;
      int row = o >> 7;
      int cs = ((o >> 4) & 7) ^ (row & 7);  // pre-swizzled global source chunk
      gload_lds16(gK + (size_t)row * 6144 + cs * 16, (char*)sK[buf] + ch * 1024);
      gload_lds16(gV + (size_t)row * 4096 + cs * 16, (char*)sV[buf] + ch * 1024);
    }
  };

  const int tstart = cch ? 16 : 0;
  const int tend = cch ? (q + 1) : (single ? (q + 1) : 16);
  int cur = 0;
  stage(tstart * 64, 0);
  __syncthreads();
  for (int t = tstart; t < tend; ++t) {
    const int kv0 = t * 64;
    if (t + 1 < tend) stage((t + 1) * 64, cur ^ 1);  // prefetch next tile
    const bool active = (kv0 <= wq0 + 15);
    if (active) {
      f32x4 s[4];
#pragma unroll
      for (int ki = 0; ki < 4; ++ki) s[ki] = (f32x4){0.f, 0.f, 0.f, 0.f};
#pragma unroll
      for (int ks = 0; ks < 2; ++ks) {
        bf16x8 bk[4];
#pragma unroll
        for (int ki = 0; ki < 4; ++ki) {
          int row = ki * 16 + l15;
          int cc = (ks * 4 + l4) ^ (row & 7);
          bk[ki] = *(const bf16x8*)((const char*)sK[cur] + row * 128 + cc * 16);
        }
#pragma unroll
        for (int ki = 0; ki < 4; ++ki)
          s[ki] = mfma16(bk[ki], qf[ks], s[ki]);
      }
      if (kv0 + 63 > wq0) {  // causal mask (boundary tiles only)
        int qa = wq0 + l15;
#pragma unroll
        for (int ki = 0; ki < 4; ++ki) {
          int kvb = kv0 + ki * 16 + l4 * 4;
#pragma unroll
          for (int rr = 0; rr < 4; ++rr)
            if (kvb + rr > qa) s[ki][rr] = -1e30f;
        }
      }
      // online softmax, per-lane row; defer-max (THR=8, log2 domain)
      float rm = s[0][0];
#pragma unroll
      for (int ki = 0; ki < 4; ++ki)
#pragma unroll
        for (int rr = 0; rr < 4; ++rr)
          rm = fmaxf(rm, s[ki][rr]);
      rm = fmaxf(rm, __shfl_xor(rm, 16));
      rm = fmaxf(rm, __shfl_xor(rm, 32));
      float mo = m;
      float mn;
      if (__all(rm <= mo + 8.f)) {
        mn = mo;  // stable: skip rescale, P bounded by 2^8
      } else {
        mn = fmaxf(mo, rm);
        float f = exp2f(mo - mn);
        m = mn;
        lsum *= f;
#pragma unroll
        for (int di = 0; di < 4; ++di)
#pragma unroll
          for (int rr = 0; rr < 4; ++rr)
            oacc[di][rr] *= f;
      }
      u32 pk_[4][2];
      float rs = 0.f;
#pragma unroll
      for (int ki = 0; ki < 4; ++ki) {
        float p0 = exp2f(s[ki][0] - mn);
        float p1 = exp2f(s[ki][1] - mn);
        float p2 = exp2f(s[ki][2] - mn);
        float p3 = exp2f(s[ki][3] - mn);
        rs += (p0 + p1) + (p2 + p3);
        pk_[ki][0] = cvtpk(p0, p1);
        pk_[ki][1] = cvtpk(p2, p3);
      }
      rs += __shfl_xor(rs, 16);
      rs += __shfl_xor(rs, 32);
      lsum += rs;
      // PV: V column permutation makes k-index mapping match on both operands
#pragma unroll
      for (int ks = 0; ks < 2; ++ks) {
        u32x4 w0 = {pk_[2 * ks][0], pk_[2 * ks][1], pk_[2 * ks + 1][0], pk_[2 * ks + 1][1]};
        bf16x8 pb = __builtin_bit_cast(bf16x8, w0);
#pragma unroll
        for (int di = 0; di < 4; ++di) {
          int row = di * 16 + l15;
          int cc = (ks * 4 + l4) ^ (row & 7);
          bf16x8 bv = *(const bf16x8*)((const char*)sV[cur] + row * 128 + cc * 16);
          oacc[di] = mfma16(bv, pb, oacc[di]);
        }
      }
    }
    __syncthreads();  // drains vmcnt(0): publishes buf[cur^1]
    cur ^= 1;
  }
  if (single) {
    float inv = 1.f / lsum;
    size_t rowb = (size_t)(b * 2048 + wq0 + l15) * 1024 + h * 64 + l4 * 4;
#pragma unroll
    for (int di = 0; di < 4; ++di) {
      uint2 w;
      w.x = cvtpk(oacc[di][0] * inv, oacc[di][1] * inv);
      w.y = cvtpk(oacc[di][2] * inv, oacc[di][3] * inv);
      *(uint2*)(yb + rowb + di * 16) = w;
    }
  } else {
    // partial: slot = (bh*16 + (q-16))*2 + cch; O fp32 [64 rows][64 d] + {m,l} per row
    int slot = (bh * 16 + (q - 16)) * 2 + cch;
    float* po = PO + ((size_t)slot * 64 + wid * 16 + l15) * 64 + l4 * 4;
#pragma unroll
    for (int di = 0; di < 4; ++di)
      *(f32x4*)(po + di * 16) = oacc[di];
    if (l4 == 0) {
      float* pm = PML + (size_t)slot * 128 + (wid * 16 + l15) * 2;
      pm[0] = m;
      pm[1] = lsum;
    }
  }
}

// ---------------- attention pass 2: combine the two kv-half partials ----------------
// Grid 512: bid -> (bh, q-16). 256 threads: row = tid>>2 (0..63), dseg = (tid&3)*16.
__global__ __launch_bounds__(256)
void k_comb(const float* __restrict__ PO, const float* __restrict__ PML, u16* __restrict__ yb)
{
  const int bid = blockIdx.x;
  const int bh = bid >> 4;
  const int q = (bid & 15) + 16;
  const int b = bh >> 4, h = bh & 15;
  const int tid = threadIdx.x;
  const int row = tid >> 2;
  const int dseg = (tid & 3) * 16;
  const int slot0 = (bh * 16 + (q - 16)) * 2;
  const int slot1 = slot0 + 1;
  float m0 = PML[(size_t)slot0 * 128 + row * 2];
  float l0 = PML[(size_t)slot0 * 128 + row * 2 + 1];
  float m1 = PML[(size_t)slot1 * 128 + row * 2];
  float l1 = PML[(size_t)slot1 * 128 + row * 2 + 1];
  float ms = fmaxf(m0, m1);
  float w0 = exp2f(m0 - ms), w1 = exp2f(m1 - ms);
  float inv = 1.f / (l0 * w0 + l1 * w1);
  const float* p0 = PO + ((size_t)slot0 * 64 + row) * 64 + dseg;
  const float* p1 = PO + ((size_t)slot1 * 64 + row) * 64 + dseg;
  u16* dst = yb + (size_t)(b * 2048 + q * 64 + row) * 1024 + h * 64 + dseg;
#pragma unroll
  for (int k = 0; k < 4; ++k) {
    f32x4 a = *(const f32x4*)(p0 + k * 4);
    f32x4 c = *(const f32x4*)(p1 + k * 4);
    uint2 w;
    w.x = cvtpk((a[0] * w0 + c[0] * w1) * inv, (a[1] * w0 + c[1] * w1) * inv);
    w.y = cvtpk((a[2] * w0 + c[2] * w1) * inv, (a[3] * w0 + c[3] * w1) * inv);
    *(uint2*)(dst + k * 4) = w;
  }
}

extern "C" void kernel_launch(void* const* d_in, const int* in_sizes, int n_in,
                              void* d_out, int out_size, void* d_ws, size_t ws_size,
                              hipStream_t stream)
{
  (void)in_sizes; (void)n_in; (void)out_size; (void)ws_size;
  const float* x      = (const float*)d_in[0];
  const float* w_attn = (const float*)d_in[1];
  const float* b_attn = (const float*)d_in[2];
  const float* w_proj = (const float*)d_in[3];
  const float* b_proj = (const float*)d_in[4];
  float* out = (float*)d_out;
  char* ws = (char*)d_ws;
  u16* xb  = (u16*)(ws);                 // 4096x1024 bf16
  u16* wab = (u16*)(ws + 8388608);       // 3072x1024 bf16
  u16* wpb = (u16*)(ws + 14680064);      // 1024x1024 bf16
  u16* qkv = (u16*)(ws + 16777216);      // 4096x3072 bf16 (v region unused)
  u16* vt  = (u16*)(ws + 41943040);      // 32x64x2048 bf16 (permuted cols)
  u16* yb  = (u16*)(ws + 50331648);      // 4096x1024 bf16
  float* PO  = (float*)(ws + 58720256);  // 1024 slots x 64 rows x 64 d fp32 (16.8 MB)
  float* PML = (float*)(ws + 75497472);  // 1024 slots x 64 rows x {m,l} (512 KB); end ~76 MB

  k_f2bf3<<<2048, 256, 0, stream>>>(x, w_attn, w_proj, xb, wab, wpb);
  k_gemm_bt<128, 128, 0><<<dim3(24, 32), 256, 0, stream>>>(xb, wab, b_attn, qkv, vt, 4096, 3072, 1024);
  k_attn<<<1536, 256, 0, stream>>>(qkv, vt, yb, PO, PML);
  k_comb<<<512, 256, 0, stream>>>(PO, PML, yb);
  k_gemm_bt<64, 128, 1><<<dim3(8, 64), 256, 0, stream>>>(yb, wpb, b_proj, out, nullptr, 4096, 1024, 1024);
}